// Round 22
// baseline (224.640 us; speedup 1.0000x reference)
//
#include <hip/hip_runtime.h>
#include <hip/hip_bf16.h>
#include <math.h>

// ---- problem constants ----
#define BB 2
#define HH 50
#define WW 50
#define NN 2500            // H*W
#define PP 4
#define LRELU_SLOPE 0.2f
#define ZTOL 1e-9f
#define PXB2 10            // ceil(2500/256)
#define ADJW 64            // compact adjacency width
#define WCAP 40            // per-wave staging cap

static inline int cdiv(int a, int b) { return (a + b - 1) / b; }

__device__ __forceinline__ float sigmoidf_(float v) { return 1.0f / (1.0f + expf(-v)); }

// ---------- enc conv1 (3->32) with fused sigmoid ----------
__launch_bounds__(256)
__global__ void k_conv_enc1(const float* __restrict__ x, const float* __restrict__ wre,
                            const float* __restrict__ bias, float* __restrict__ out) {
    int bx = blockIdx.x;
    int pxb = bx % PXB2;
    int ocg = (bx / PXB2) % 4;
    int b = bx / (PXB2 * 4);
    int px = pxb * 256 + threadIdx.x;
    bool valid = px < NN;
    int xx0 = px % WW, yy0 = px / WW;
    float acc[8];
#pragma unroll
    for (int o = 0; o < 8; ++o) acc[o] = 0.f;
    for (int ic = 0; ic < 3; ++ic) {
        const float* ip = x + ((size_t)(b * 3 + ic)) * NN;
        float v[9];
#pragma unroll
        for (int ky = 0; ky < 3; ++ky) {
            int yy = yy0 + ky - 1;
#pragma unroll
            for (int kx = 0; kx < 3; ++kx) {
                int xx = xx0 + kx - 1;
                bool ok = valid && yy >= 0 && yy < HH && xx >= 0 && xx < WW;
                v[ky * 3 + kx] = ok ? sigmoidf_(ip[yy * WW + xx]) : 0.f;
            }
        }
        const float* wp = wre + (size_t)ic * 9 * 32 + ocg * 8;
#pragma unroll
        for (int tp = 0; tp < 9; ++tp) {
            float vv = v[tp];
#pragma unroll
            for (int o = 0; o < 8; ++o) acc[o] += wp[tp * 32 + o] * vv;
        }
    }
    if (valid) {
#pragma unroll
        for (int o = 0; o < 8; ++o) {
            int oc = ocg * 8 + o;
            out[((size_t)(b * 32 + oc)) * NN + px] = fmaxf(acc[o] + bias[oc], 0.f);
        }
    }
}

// ---------- generic chunked conv3x3 partials (enc2 path) ----------
template<int OCT>
__launch_bounds__(256)
__global__ void k_conv_part(const float* __restrict__ in, const float* __restrict__ wre,
                            float* __restrict__ part, int Cin, int OC, int nocg,
                            int nchunks, int icchunk, float padval) {
    int bx = blockIdx.x;
    int pxb = bx % PXB2; bx /= PXB2;
    int ocg = bx % nocg; bx /= nocg;
    int chunk = bx % nchunks;
    int b = bx / nchunks;
    int px = pxb * 256 + threadIdx.x;
    bool valid = px < NN;
    int xx0 = px % WW, yy0 = px / WW;

    float acc[OCT];
#pragma unroll
    for (int o = 0; o < OCT; ++o) acc[o] = 0.f;

    int ic0 = chunk * icchunk;
    int ic1 = ic0 + icchunk; if (ic1 > Cin) ic1 = Cin;

    for (int ic = ic0; ic < ic1; ++ic) {
        const float* ip = in + ((size_t)(b * Cin + ic)) * NN;
        float v[9];
#pragma unroll
        for (int ky = 0; ky < 3; ++ky) {
            int yy = yy0 + ky - 1;
#pragma unroll
            for (int kx = 0; kx < 3; ++kx) {
                int xx = xx0 + kx - 1;
                bool ok = valid && yy >= 0 && yy < HH && xx < WW && xx >= 0;
                v[ky * 3 + kx] = ok ? ip[yy * WW + xx] : padval;
            }
        }
        const float* wp = wre + (size_t)ic * 9 * OC + ocg * OCT;
#pragma unroll
        for (int tp = 0; tp < 9; ++tp) {
            float vv = v[tp];
#pragma unroll
            for (int o = 0; o < OCT; ++o) acc[o] += wp[tp * OC + o] * vv;
        }
    }
    if (valid) {
#pragma unroll
        for (int o = 0; o < OCT; ++o)
            part[(((size_t)chunk * BB + b) * OC + ocg * OCT + o) * NN + px] = acc[o];
    }
}

// ---------- dec conv1 (128->32) with in-block channel-attention MLP ----------
// grid: pxb(10) x ocg(2) x chunk(4) x b(2) = 160 blocks; icchunk=32, OCT=16.
__launch_bounds__(256)
__global__ void k_conv_dec1(const float* __restrict__ in, const float* __restrict__ wre,
                            const float* __restrict__ att,
                            const float* __restrict__ w1, const float* __restrict__ b1,
                            const float* __restrict__ w2, const float* __restrict__ b2,
                            float* __restrict__ part) {
    __shared__ float att_s[128];
    __shared__ float hsh[128];
    __shared__ float attf[128];

    int tid = threadIdx.x;
    int bx = blockIdx.x;
    int pxb = bx % PXB2; bx /= PXB2;
    int ocg = bx % 2; bx /= 2;
    int chunk = bx % 4;
    int b = bx / 4;

    // ---- in-block camlp: attf = sigmoid(W2 relu(W1 att + b1) + b2) ----
    if (tid < 128) att_s[tid] = att[b * 128 + tid];
    __syncthreads();
    if (tid < 128) {
        float acc = b1[tid];
        const float* wr = w1 + (size_t)tid * 128;
        for (int k = 0; k < 128; ++k) acc += att_s[k] * wr[k];
        hsh[tid] = fmaxf(acc, 0.f);
    }
    __syncthreads();
    if (tid < 128) {
        float acc = b2[tid];
        const float* wr = w2 + (size_t)tid * 128;
        for (int k = 0; k < 128; ++k) acc += hsh[k] * wr[k];
        attf[tid] = sigmoidf_(acc);
    }
    __syncthreads();

    int px = pxb * 256 + tid;
    bool valid = px < NN;
    int xx0 = px % WW, yy0 = px / WW;

    float acc[16];
#pragma unroll
    for (int o = 0; o < 16; ++o) acc[o] = 0.f;

    int ic0 = chunk * 32;
    for (int ic = ic0; ic < ic0 + 32; ++ic) {
        const float* ip = in + ((size_t)(b * 128 + ic)) * NN;
        float attv = attf[ic];
        float v[9];
#pragma unroll
        for (int ky = 0; ky < 3; ++ky) {
            int yy = yy0 + ky - 1;
#pragma unroll
            for (int kx = 0; kx < 3; ++kx) {
                int xx = xx0 + kx - 1;
                bool ok = valid && yy >= 0 && yy < HH && xx < WW && xx >= 0;
                v[ky * 3 + kx] = ok ? ip[yy * WW + xx] * attv : -999.0f;
            }
        }
        const float* wp = wre + (size_t)ic * 9 * 32 + ocg * 16;
#pragma unroll
        for (int tp = 0; tp < 9; ++tp) {
            float vv = v[tp];
#pragma unroll
            for (int o = 0; o < 16; ++o) acc[o] += wp[tp * 32 + o] * vv;
        }
    }
    if (valid) {
#pragma unroll
        for (int o = 0; o < 16; ++o)
            part[(((size_t)chunk * BB + b) * 32 + ocg * 16 + o) * NN + px] = acc[o];
    }
}

// ---------- reduce chunks + bias + relu (dec path) ----------
__global__ void k_conv_reduce(const float* __restrict__ part, const float* __restrict__ bias,
                              float* __restrict__ out, float* __restrict__ xTout,
                              int OCr, int nchunks) {
    int idx = blockIdx.x * blockDim.x + threadIdx.x;
    int total = BB * OCr * NN;
    if (idx >= total) return;
    int px = idx % NN;
    int oc = (idx / NN) % OCr;
    int b = idx / (NN * OCr);
    float s = bias[oc];
    for (int c = 0; c < nchunks; ++c)
        s += part[(((size_t)c * BB + b) * OCr + oc) * NN + px];
    s = fmaxf(s, 0.f);
    if (out)   out[((size_t)(b * OCr + oc)) * NN + px] = s;
    if (xTout) xTout[((size_t)b * NN + px) * OCr + oc] = s;
}

// ---------- dec conv2 (32->1): 4-wave ic-split, 64 px per block ----------
__launch_bounds__(256)
__global__ void k_conv_dec2(const float* __restrict__ in, const float* __restrict__ wre,
                            const float* __restrict__ bias, float* __restrict__ out) {
    __shared__ float red[4][64];
    int tid = threadIdx.x;
    int w = tid >> 6, lane = tid & 63;
    int blk = blockIdx.x;               // BB * 40
    int pxb = blk % 40;
    int b = blk / 40;
    int px = pxb * 64 + lane;
    bool valid = px < NN;
    int xx0 = px % WW, yy0 = px / WW;
    float acc = 0.f;
    for (int ic = w * 8; ic < w * 8 + 8; ++ic) {
        const float* ip = in + ((size_t)(b * 32 + ic)) * NN;
#pragma unroll
        for (int ky = 0; ky < 3; ++ky) {
            int yy = yy0 + ky - 1;
#pragma unroll
            for (int kx = 0; kx < 3; ++kx) {
                int xx = xx0 + kx - 1;
                bool ok = valid && yy >= 0 && yy < HH && xx >= 0 && xx < WW;
                float v = ok ? ip[yy * WW + xx] : -999.0f;
                acc += v * wre[ic * 9 + ky * 3 + kx];
            }
        }
    }
    red[w][lane] = acc;
    __syncthreads();
    if (w == 0 && valid) {
        float s = red[0][lane] + red[1][lane] + red[2][lane] + red[3][lane];
        out[(size_t)b * NN + px] = fmaxf(s + bias[0], 0.f);
    }
}

// ---------- fused adjacency build + compact (+ repack in tail blocks) ----------
__launch_bounds__(256, 8)
__global__ void k_build_compact(const float* __restrict__ S,
                                int2* __restrict__ adjC, int* __restrict__ cntC,
                                const float* __restrict__ e1, const float* __restrict__ e2,
                                const float* __restrict__ dd1, const float* __restrict__ dd2,
                                float* __restrict__ r1, float* __restrict__ r2,
                                float* __restrict__ r3, float* __restrict__ r4) {
    int row = blockIdx.x;               // 2*BB*NN rows; tail blocks do repack
    if (row >= 2 * BB * NN) {
        int i = (row - 2 * BB * NN) * 256 + threadIdx.x;
        if (i < 32 * 3 * 9)  { int oc = i / 27;  int rem = i % 27;  int ic = rem / 9; int tp = rem % 9; r1[(ic * 9 + tp) * 32 + oc] = e1[i]; }
        if (i < 32 * 32 * 9) { int oc = i / 288; int rem = i % 288; int ic = rem / 9; int tp = rem % 9; r2[(ic * 9 + tp) * 32 + oc] = e2[i]; }
        if (i < 32 * 128 * 9){ int oc = i / 1152;int rem = i % 1152;int ic = rem / 9; int tp = rem % 9; r3[(ic * 9 + tp) * 32 + oc] = dd1[i]; }
        if (i < 1 * 32 * 9)  { int oc = 0;       int rem = i;       int ic = rem / 9; int tp = rem % 9; r4[(ic * 9 + tp) * 1  + oc] = dd2[i]; }
        return;
    }
    __shared__ int2 stage[4][WCAP];
    __shared__ int  wcnt[4];

    int i = row % NN;
    int b = (row / NN) % BB;
    int s = row / (NN * BB);
    const float4* Srow = (const float4*)(S + (((size_t)(b * 2 + s)) * NN + i) * NN);

    int tid = threadIdx.x;
    int w = tid >> 6, lane = tid & 63;
    int q0 = w * 157;
    int q1 = (w == 3) ? 625 : (q0 + 157);

    float4 fv[3];
#pragma unroll
    for (int r = 0; r < 3; ++r) {
        int q = q0 + r * 64 + lane;
        fv[r] = (q < q1) ? Srow[q] : make_float4(0.f, 0.f, 0.f, 0.f);
    }

    unsigned long long below = (lane == 63) ? 0x7fffffffffffffffull
                                            : ((1ull << lane) - 1ull);
    int cnt = 0;
#pragma unroll
    for (int r = 0; r < 3; ++r) {
        float4 f = fv[r];
        unsigned long long b0 = __ballot(fabsf(f.x) > ZTOL);
        unsigned long long b1 = __ballot(fabsf(f.y) > ZTOL);
        unsigned long long b2 = __ballot(fabsf(f.z) > ZTOL);
        unsigned long long b3 = __ballot(fabsf(f.w) > ZTOL);
        int rk = __popcll(b0 & below) + __popcll(b1 & below) +
                 __popcll(b2 & below) + __popcll(b3 & below);
        int j0 = (q0 + r * 64 + lane) * 4;
        int idx = cnt + rk;
        if ((b0 >> lane) & 1) { if (idx < WCAP) stage[w][idx] = make_int2(j0 + 0, __float_as_int(f.x)); ++idx; }
        if ((b1 >> lane) & 1) { if (idx < WCAP) stage[w][idx] = make_int2(j0 + 1, __float_as_int(f.y)); ++idx; }
        if ((b2 >> lane) & 1) { if (idx < WCAP) stage[w][idx] = make_int2(j0 + 2, __float_as_int(f.z)); ++idx; }
        if ((b3 >> lane) & 1) { if (idx < WCAP) stage[w][idx] = make_int2(j0 + 3, __float_as_int(f.w)); ++idx; }
        cnt += __popcll(b0) + __popcll(b1) + __popcll(b2) + __popcll(b3);
    }
    if (lane == 0) wcnt[w] = (cnt < WCAP) ? cnt : WCAP;
    __syncthreads();

    int c0 = wcnt[0], c1 = wcnt[1], c2 = wcnt[2], c3 = wcnt[3];
    int base = (w == 0) ? 0 : (w == 1) ? c0 : (w == 2) ? (c0 + c1) : (c0 + c1 + c2);
    int myc = wcnt[w];
    for (int k = lane; k < myc; k += 64) {
        int dstb = base + k;
        if (dstb < ADJW) adjC[(size_t)row * ADJW + dstb] = stage[w][k];
    }
    if (tid == 0) {
        int total = c0 + c1 + c2 + c3;
        cntC[row] = (total < ADJW) ? total : ADJW;
    }
}

// ---------- per-head masked softmax * S ----------
__device__ __forceinline__ float4 softmax4(float4 s1f, float4 s2f, int lane, int cnt, float valr) {
    float e[PP] = { s1f.x + s2f.x, s1f.y + s2f.y, s1f.z + s2f.z, s1f.w + s2f.w };
    float w[PP];
#pragma unroll
    for (int p = 0; p < PP; ++p) {
        float v = e[p];
        v = (v < 0.f) ? LRELU_SLOPE * v : v;
        v = (lane < cnt) ? v : -1e30f;
        float mx = v;
#pragma unroll
        for (int m = 32; m >= 1; m >>= 1) mx = fmaxf(mx, __shfl_xor(mx, m));
        float ex = (lane < cnt) ? expf(v - mx) : 0.f;
        float sm = ex;
#pragma unroll
        for (int m = 32; m >= 1; m >>= 1) sm += __shfl_xor(sm, m);
        w[p] = (cnt > 0) ? ex / sm * valr : 0.f;
    }
    return make_float4(w[0], w[1], w[2], w[3]);
}

// ---------- emit s1/s2 (lane holds y element `lane`, PF<=64) ----------
template<int PF>
__device__ __forceinline__ void emit_one(const float* __restrict__ a,
                                         float4* __restrict__ s1E, float4* __restrict__ s2E,
                                         float yl, int lane, int node) {
    float r1[PP], r2[PP];
#pragma unroll
    for (int p = 0; p < PP; ++p) {
        float v1 = (lane < PF) ? a[p * 2 * PF + lane] * yl : 0.f;
        float v2 = (lane < PF) ? a[p * 2 * PF + PF + lane] * yl : 0.f;
#pragma unroll
        for (int m = 32; m >= 1; m >>= 1) { v1 += __shfl_xor(v1, m); v2 += __shfl_xor(v2, m); }
        r1[p] = v1; r2[p] = v2;
    }
    if (lane == 0) {
        s1E[node] = make_float4(r1[0], r1[1], r1[2], r1[3]);
        s2E[node] = make_float4(r2[0], r2[1], r2[2], r2[3]);
    }
}

// ---------- unified GAT layer v6: ONE WAVE = ONE BLOCK = ONE NODE (grid 5000) ----------
template<int G, int F, int FZ, int ADDP, int ES, int CMAJ>
__launch_bounds__(64)
__global__ void k_gat_layer2(const float* __restrict__ xT,
                             const int2* __restrict__ adjC, const int* __restrict__ cntC,
                             const float4* __restrict__ s1A, const float4* __restrict__ s2A,
                             const float4* __restrict__ s1Z, const float4* __restrict__ s2Z,
                             const float* __restrict__ Wf, const float* __restrict__ bias,
                             const float* __restrict__ WfZ, const float* __restrict__ biasZ,
                             const float* __restrict__ prevP,
                             float* __restrict__ auxOut,
                             const float* __restrict__ aE0, float4* __restrict__ s1E0, float4* __restrict__ s2E0,
                             const float* __restrict__ aE1, float4* __restrict__ s1E1, float4* __restrict__ s2E1,
                             float* __restrict__ dst) {
    constexpr int PF = PP * F;
    __shared__ int    csh[64];
    __shared__ float4 wAsh[64];
    __shared__ float4 wZsh[FZ ? 64 : 1];
    __shared__ float  xAsh[G + 1];
    __shared__ float  z1Ash[PP][G + 1];
    __shared__ float  z1Zsh[FZ ? PP : 1][FZ ? (G + 1) : 1];
    __shared__ float  ysh[ES ? (PF + 1) : 1];

    int lane = threadIdx.x;
    int node = blockIdx.x;
    int b = node / NN, i = node % NN;

    // ---- sparse phase ----
    {
        if (lane < G) xAsh[lane] = xT[(size_t)node * G + lane];
        int cnt = cntC[node];
        int colr = 0; float valr = 0.f;
        if (lane < cnt) {
            int2 e = adjC[(size_t)node * ADJW + lane];
            colr = e.x;
            valr = __int_as_float(e.y);
        }
        float4 s2fA = make_float4(0.f, 0.f, 0.f, 0.f);
        float4 s2fZ = make_float4(0.f, 0.f, 0.f, 0.f);
        if (lane < cnt) {
            s2fA = s2A[(size_t)b * NN + colr];
            if constexpr (FZ > 0) s2fZ = s2Z[(size_t)b * NN + colr];
        }
        csh[lane] = colr;
        wAsh[lane] = softmax4(s1A[node], s2fA, lane, cnt, valr);
        if constexpr (FZ > 0) wZsh[lane] = softmax4(s1Z[node], s2fZ, lane, cnt, valr);

        constexpr int STEP = (G == 32) ? 2 : 1;
        int sl = (G == 32) ? (lane >> 5) : 0;
        int g  = (G == 32) ? (lane & 31) : lane;
        const float* xb = xT + (size_t)b * NN * G + g;
        float zA[PP] = {0.f, 0.f, 0.f, 0.f};
        float zZ[PP] = {0.f, 0.f, 0.f, 0.f};
        int jj = sl;
        for (; jj + 7 * STEP < cnt; jj += 8 * STEP) {
            int c[8];
            float xv[8];
#pragma unroll
            for (int u = 0; u < 8; ++u) c[u] = csh[jj + u * STEP];
#pragma unroll
            for (int u = 0; u < 8; ++u) xv[u] = xb[(size_t)c[u] * G];
#pragma unroll
            for (int u = 0; u < 8; ++u) {
                float4 wa = wAsh[jj + u * STEP];
                zA[0] += wa.x * xv[u]; zA[1] += wa.y * xv[u];
                zA[2] += wa.z * xv[u]; zA[3] += wa.w * xv[u];
                if constexpr (FZ > 0) {
                    float4 wz = wZsh[jj + u * STEP];
                    zZ[0] += wz.x * xv[u]; zZ[1] += wz.y * xv[u];
                    zZ[2] += wz.z * xv[u]; zZ[3] += wz.w * xv[u];
                }
            }
        }
        for (; jj < cnt; jj += STEP) {
            float xv = xb[(size_t)csh[jj] * G];
            float4 wa = wAsh[jj];
            zA[0] += wa.x * xv; zA[1] += wa.y * xv; zA[2] += wa.z * xv; zA[3] += wa.w * xv;
            if constexpr (FZ > 0) {
                float4 wz = wZsh[jj];
                zZ[0] += wz.x * xv; zZ[1] += wz.y * xv; zZ[2] += wz.z * xv; zZ[3] += wz.w * xv;
            }
        }
        if (G == 32) {
#pragma unroll
            for (int p = 0; p < PP; ++p) {
                zA[p] += __shfl_xor(zA[p], 32);
                if constexpr (FZ > 0) zZ[p] += __shfl_xor(zZ[p], 32);
            }
        }
        if (sl == 0) {
#pragma unroll
            for (int p = 0; p < PP; ++p) {
                z1Ash[p][g] = zA[p];
                if constexpr (FZ > 0) z1Zsh[p][g] = zZ[p];
            }
        }
    }
    // same-wave LDS deps are in-order; no barrier needed.

    // ---- dense own projection: W direct from global (L2-cached) ----
    for (int t = lane; t < PF; t += 64) {
        int p = t / F, f = t % F;
        const float* W0 = Wf + (size_t)(p * 2) * G * F + f;
        const float* W1 = W0 + G * F;
        float y = bias[f];
#pragma unroll 16
        for (int g = 0; g < G; ++g)
            y += xAsh[g] * W0[(size_t)g * F] + z1Ash[p][g] * W1[(size_t)g * F];
        if (ADDP) y += prevP[(size_t)node * PF + t];
        if (CMAJ) dst[((size_t)(b * PF + t)) * NN + i] = y;
        else      dst[(size_t)node * PF + t] = y;
        if (ES) ysh[t] = y;
    }

    // ---- aux projection (second attention set, same x/adjacency) ----
    if constexpr (FZ > 0) {
        for (int t = lane; t < PP * FZ; t += 64) {
            int p = t / FZ, f = t % FZ;
            const float* V0 = WfZ + (size_t)(p * 2) * G * FZ + f;
            const float* V1 = V0 + G * FZ;
            float y = biasZ[f];
#pragma unroll 16
            for (int g = 0; g < G; ++g)
                y += xAsh[g] * V0[(size_t)g * FZ] + z1Zsh[p][g] * V1[(size_t)g * FZ];
            auxOut[(size_t)node * (PP * FZ) + t] = y;
        }
    }

    // ---- s1/s2 emit for next layer(s) ----
    if (ES) {
        float yl = (lane < PF) ? ysh[lane] : 0.f;
        emit_one<PF>(aE0, s1E0, s2E0, yl, lane, node);
        if (ES >= 2) emit_one<PF>(aE1, s1E1, s2E1, yl, lane, node);
    }
}

// ---------- s1/s2 for f0 FUSED with enc2 chunk-reduce ----------
template<int G>
__launch_bounds__(256)
__global__ void k_s1s2T_fused(const float* __restrict__ part, const float* __restrict__ bias,
                              float* __restrict__ xTout,
                              const float* __restrict__ aA, float4* __restrict__ s1A, float4* __restrict__ s2A,
                              const float* __restrict__ aB, float4* __restrict__ s1B, float4* __restrict__ s2B) {
    constexpr int NPB = 16;
    __shared__ float xsh[NPB][G + 1];
    __shared__ float ash[2][2][PP][G];
    __shared__ float ysh[NPB][17];

    int tid = threadIdx.x;
    int node0 = blockIdx.x * NPB;

    for (int idx = tid; idx < PP * 2 * G; idx += 256) {
        int p = idx / (2 * G), r = idx % (2 * G);
        int which = r / G, g = r % G;
        ash[0][which][p][g] = aA[idx];
        if (aB) ash[1][which][p][g] = aB[idx];
    }
    for (int idx = tid; idx < NPB * G; idx += 256) {
        int nl = idx & (NPB - 1), g = idx >> 4;
        int node = node0 + nl;
        float s = 0.f;
        if (node < BB * NN) {
            int b = node / NN, px = node % NN;
            s = bias[g];
            for (int c = 0; c < 4; ++c)
                s += part[(((size_t)c * BB + b) * G + g) * NN + px];
            s = fmaxf(s, 0.f);
        }
        xsh[nl][g] = s;
    }
    __syncthreads();
    for (int idx = tid; idx < NPB * G; idx += 256) {
        int nl = idx / G, g = idx % G;
        int node = node0 + nl;
        if (node < BB * NN) xTout[(size_t)node * G + g] = xsh[nl][g];
    }

    {
        int nl = tid / 16, o = tid % 16;
        int set = o / 8, which = (o / 4) % 2, p = o % 4;
        float acc = 0.f;
        if (set == 0 || aB) {
#pragma unroll
            for (int g = 0; g < G; ++g) acc += ash[set][which][p][g] * xsh[nl][g];
        }
        ysh[nl][o] = acc;
    }
    __syncthreads();

    if (tid < NPB * 4) {
        int nl = tid / 4, q = tid % 4;
        int node = node0 + nl;
        if (node < BB * NN) {
            int base = (q / 2) * 8 + (q % 2) * 4;
            float4 v = make_float4(ysh[nl][base + 0], ysh[nl][base + 1],
                                   ysh[nl][base + 2], ysh[nl][base + 3]);
            if (q == 0) s1A[node] = v;
            else if (q == 1) s2A[node] = v;
            else if (q == 2) { if (aB) s1B[node] = v; }
            else             { if (aB) s2B[node] = v; }
        }
    }
}

// ---------- att = max over spatial ----------
__global__ void k_attmax(const float* __restrict__ d, float* __restrict__ att) {
    int wid = blockIdx.x;
    int lane = threadIdx.x;
    const float4* row = (const float4*)(d + (size_t)wid * NN);
    float m = -1e30f;
    for (int q = lane; q < 625; q += 64) {
        float4 f = row[q];
        m = fmaxf(m, fmaxf(fmaxf(f.x, f.y), fmaxf(f.z, f.w)));
    }
    for (int s = 32; s >= 1; s >>= 1) m = fmaxf(m, __shfl_xor(m, s));
    if (lane == 0) att[wid] = m;
}

// ---------- MLP layer 1: fully batched float4 loads ----------
__launch_bounds__(64)
__global__ void k_mlp1(const float* __restrict__ flat, const float* __restrict__ w,
                       const float* __restrict__ bias, float* __restrict__ out) {
    int wid = blockIdx.x;
    int lane = threadIdx.x;
    int o = wid % 512;
    int b = wid / 512;
    const float4* fr = (const float4*)(flat + (size_t)b * NN);     // 625 quads
    const float4* wr = (const float4*)(w + (size_t)o * NN);
    float4 fv[10], wv[10];
#pragma unroll
    for (int k = 0; k < 10; ++k) {
        int q = lane + 64 * k;
        bool ok = q < 625;
        fv[k] = ok ? fr[q] : make_float4(0.f, 0.f, 0.f, 0.f);
        wv[k] = ok ? wr[q] : make_float4(0.f, 0.f, 0.f, 0.f);
    }
    float acc = 0.f;
#pragma unroll
    for (int k = 0; k < 10; ++k)
        acc += fv[k].x * wv[k].x + fv[k].y * wv[k].y +
               fv[k].z * wv[k].z + fv[k].w * wv[k].w;
    for (int s = 32; s >= 1; s >>= 1) acc += __shfl_xor(acc, s);
    if (lane == 0) out[wid] = fmaxf(acc + bias[o], 0.0f);
}

__global__ void k_mlp2(const float* __restrict__ m, const float* __restrict__ w,
                       const float* __restrict__ bias, float* __restrict__ out) {
    int wid = blockIdx.x;
    int lane = threadIdx.x;
    int o = wid % 5;
    int b = wid / 5;
    const float* mr = m + b * 512;
    const float* wr = w + o * 512;
    float acc = 0.f;
    for (int k = lane; k < 512; k += 64) acc += mr[k] * wr[k];
    for (int s = 32; s >= 1; s >>= 1) acc += __shfl_xor(acc, s);
    if (lane == 0) out[wid] = 1.0f / (1.0f + expf(-(acc + bias[o])));
}

extern "C" void kernel_launch(void* const* d_in, const int* in_sizes, int n_in,
                              void* d_out, int out_size, void* d_ws, size_t ws_size,
                              hipStream_t stream) {
    const float* x       = (const float*)d_in[0];
    const float* Slist   = (const float*)d_in[1];
    const float* enc_w1  = (const float*)d_in[2];
    const float* enc_b1  = (const float*)d_in[3];
    const float* enc_w2  = (const float*)d_in[4];
    const float* enc_b2  = (const float*)d_in[5];
    const float* d0_a = (const float*)d_in[6];  const float* d0_W = (const float*)d_in[7];  const float* d0_b = (const float*)d_in[8];
    const float* d1_a = (const float*)d_in[9];  const float* d1_W = (const float*)d_in[10]; const float* d1_b = (const float*)d_in[11];
    const float* u0_a = (const float*)d_in[12]; const float* u0_W = (const float*)d_in[13]; const float* u0_b = (const float*)d_in[14];
    const float* u1_a = (const float*)d_in[15]; const float* u1_W = (const float*)d_in[16]; const float* u1_b = (const float*)d_in[17];
    const float* s0_a = (const float*)d_in[18]; const float* s0_W = (const float*)d_in[19]; const float* s0_b = (const float*)d_in[20];
    const float* s1_a = (const float*)d_in[21]; const float* s1_W = (const float*)d_in[22]; const float* s1_b = (const float*)d_in[23];
    const float* ca_w1 = (const float*)d_in[24]; const float* ca_b1 = (const float*)d_in[25];
    const float* ca_w2 = (const float*)d_in[26]; const float* ca_b2 = (const float*)d_in[27];
    const float* dec_w1 = (const float*)d_in[28]; const float* dec_b1 = (const float*)d_in[29];
    const float* dec_w2 = (const float*)d_in[30]; const float* dec_b2 = (const float*)d_in[31];
    const float* mlp_w1 = (const float*)d_in[32]; const float* mlp_b1 = (const float*)d_in[33];
    const float* mlp_w2 = (const float*)d_in[34]; const float* mlp_b2 = (const float*)d_in[35];
    float* out = (float*)d_out;

    // ---- workspace layout (f32 elements) ----
    float* ws = (float*)d_ws;
    size_t off = 0;
    auto alloc = [&](size_t n) { float* p = ws + off; off += n; return p; };
    float* h1    = alloc((size_t)BB * 32 * NN);
    float* xT_f0 = alloc((size_t)BB * NN * 32);
    float* xT_f1 = alloc((size_t)BB * NN * 64);
    float* xT_f2 = alloc((size_t)BB * NN * 32);
    float* xT_g1 = alloc((size_t)BB * NN * 64);
    float* g2    = alloc((size_t)BB * 128 * NN);
    int2*  adjC = (int2*)alloc((size_t)2 * BB * NN * ADJW * 2);
    int*   cntC = (int*)alloc((size_t)2 * BB * NN);
    float4* s1_d0 = (float4*)alloc(4 * BB * NN); float4* s2_d0 = (float4*)alloc(4 * BB * NN);
    float4* s1_s0 = (float4*)alloc(4 * BB * NN); float4* s2_s0 = (float4*)alloc(4 * BB * NN);
    float4* s1_d1 = (float4*)alloc(4 * BB * NN); float4* s2_d1 = (float4*)alloc(4 * BB * NN);
    float4* s1_sc1= (float4*)alloc(4 * BB * NN); float4* s2_sc1= (float4*)alloc(4 * BB * NN);
    float4* s1_u0 = (float4*)alloc(4 * BB * NN); float4* s2_u0 = (float4*)alloc(4 * BB * NN);
    float4* s1_u1 = (float4*)alloc(4 * BB * NN); float4* s2_u1 = (float4*)alloc(4 * BB * NN);
    float* g1p   = alloc((size_t)BB * NN * 64);
    float* g2p   = alloc((size_t)BB * NN * 128);
    float* att   = alloc(BB * 128);
    float* dec1o = alloc((size_t)BB * 32 * NN);
    float* dec2o = alloc((size_t)BB * NN);
    float* mbuf  = alloc((size_t)BB * 512);
    float* wre1  = alloc(32 * 3 * 9);
    float* wre2  = alloc(32 * 32 * 9);
    float* wre3  = alloc(32 * 128 * 9);
    float* wre4  = alloc(1 * 32 * 9);
    float* partial = alloc((size_t)8 * BB * 32 * NN);
    (void)ws_size;

    const int T = 256;
    const int NNODE = BB * NN;          // 5000
    const int2* adjC0 = adjC;
    const int2* adjC1 = adjC + (size_t)NNODE * ADJW;
    const int* cnt0 = cntC;
    const int* cnt1 = cntC + NNODE;

    // 0. fused adjacency build+compact + weight repack (tail blocks)
    k_build_compact<<<2 * NNODE + 144, 256, 0, stream>>>(Slist, adjC, cntC,
                                                         enc_w1, enc_w2, dec_w1, dec_w2,
                                                         wre1, wre2, wre3, wre4);
    // 1. encoder
    k_conv_enc1<<<BB * 4 * PXB2, 256, 0, stream>>>(x, wre1, enc_b1, h1);
    k_conv_part<8><<<BB * 4 * 4 * PXB2, 256, 0, stream>>>(h1, wre2, partial,
                                                          32, 32, 4, 4, 8, 0.0f);
    // 2. s1/s2 on f0 (fused enc2 chunk-reduce) for d0 + s0
    k_s1s2T_fused<32><<<cdiv(NNODE, 16), 256, 0, stream>>>(partial, enc_b2, xT_f0,
                                                           d0_a, s1_d0, s2_d0,
                                                           s0_a, s1_s0, s2_s0);
    // 3. L1: f1 = gat(f0,S0,d0); aux s0-proj -> g2p; emit d1, sc1
    k_gat_layer2<32,16,32, 0, 2, 0><<<NNODE, 64, 0, stream>>>(
        xT_f0, adjC0, cnt0,
        s1_d0, s2_d0, s1_s0, s2_s0,
        d0_W, d0_b, s0_W, s0_b,
        nullptr, g2p,
        d1_a, s1_d1, s2_d1, s1_a, s1_sc1, s2_sc1, xT_f1);
    // 4. L2: f2 = gat(f1,S1,d1); aux sc1-proj -> g1p; emit u0
    k_gat_layer2<64,8,16, 0, 1, 0><<<NNODE, 64, 0, stream>>>(
        xT_f1, adjC1, cnt1,
        s1_d1, s2_d1, s1_sc1, s2_sc1,
        d1_W, d1_b, s1_W, s1_b,
        nullptr, g1p,
        u0_a, s1_u0, s2_u0, nullptr, nullptr, nullptr, xT_f2);
    // 5. L3: g1 = gat(f2,S1,u0) + g1p; emit u1
    k_gat_layer2<32,16,0, 1, 1, 0><<<NNODE, 64, 0, stream>>>(
        xT_f2, adjC1, cnt1,
        s1_u0, s2_u0, nullptr, nullptr,
        u0_W, u0_b, nullptr, nullptr,
        g1p, nullptr,
        u1_a, s1_u1, s2_u1, nullptr, nullptr, nullptr, xT_g1);
    // 6. L4: g2 = gat(g1,S0,u1) + g2p  (channel-major out)
    k_gat_layer2<64,32,0, 1, 0, 1><<<NNODE, 64, 0, stream>>>(
        xT_g1, adjC0, cnt0,
        s1_u1, s2_u1, nullptr, nullptr,
        u1_W, u1_b, nullptr, nullptr,
        g2p, nullptr,
        nullptr, nullptr, nullptr, nullptr, nullptr, nullptr, g2);
    // 7. channel attention max (camlp fused into dec conv1)
    k_attmax<<<BB * 128, 64, 0, stream>>>(g2, att);
    // 8. decoder convs (pad -999; camlp + att-scale in-block)
    k_conv_dec1<<<BB * 4 * 2 * PXB2, 256, 0, stream>>>(g2, wre3, att,
                                                       ca_w1, ca_b1, ca_w2, ca_b2, partial);
    k_conv_reduce<<<cdiv(BB * 32 * NN, T), T, 0, stream>>>(partial, dec_b1, dec1o, nullptr, 32, 4);
    k_conv_dec2<<<BB * 40, 256, 0, stream>>>(dec1o, wre4, dec_b2, dec2o);
    // 9. MLP head
    k_mlp1<<<BB * 512, 64, 0, stream>>>(dec2o, mlp_w1, mlp_b1, mbuf);
    k_mlp2<<<BB * 5, 64, 0, stream>>>(mbuf, mlp_w2, mlp_b2, out);
}

// Round 23
// 214.541 us; speedup vs baseline: 1.0471x; 1.0471x over previous
//
#include <hip/hip_runtime.h>
#include <hip/hip_bf16.h>
#include <math.h>

// ---- problem constants ----
#define BB 2
#define HH 50
#define WW 50
#define NN 2500            // H*W
#define PP 4
#define LRELU_SLOPE 0.2f
#define ZTOL 1e-9f
#define PXB2 10            // ceil(2500/256)
#define ADJW 64            // compact adjacency width
#define WCAP 40            // per-wave staging cap

static inline int cdiv(int a, int b) { return (a + b - 1) / b; }

__device__ __forceinline__ float sigmoidf_(float v) { return 1.0f / (1.0f + expf(-v)); }

// ---------- enc conv1 (3->32) with fused sigmoid ----------
__launch_bounds__(256)
__global__ void k_conv_enc1(const float* __restrict__ x, const float* __restrict__ wre,
                            const float* __restrict__ bias, float* __restrict__ out) {
    int bx = blockIdx.x;
    int pxb = bx % PXB2;
    int ocg = (bx / PXB2) % 4;
    int b = bx / (PXB2 * 4);
    int px = pxb * 256 + threadIdx.x;
    bool valid = px < NN;
    int xx0 = px % WW, yy0 = px / WW;
    float acc[8];
#pragma unroll
    for (int o = 0; o < 8; ++o) acc[o] = 0.f;
    for (int ic = 0; ic < 3; ++ic) {
        const float* ip = x + ((size_t)(b * 3 + ic)) * NN;
        float v[9];
#pragma unroll
        for (int ky = 0; ky < 3; ++ky) {
            int yy = yy0 + ky - 1;
#pragma unroll
            for (int kx = 0; kx < 3; ++kx) {
                int xx = xx0 + kx - 1;
                bool ok = valid && yy >= 0 && yy < HH && xx >= 0 && xx < WW;
                v[ky * 3 + kx] = ok ? sigmoidf_(ip[yy * WW + xx]) : 0.f;
            }
        }
        const float* wp = wre + (size_t)ic * 9 * 32 + ocg * 8;
#pragma unroll
        for (int tp = 0; tp < 9; ++tp) {
            float vv = v[tp];
#pragma unroll
            for (int o = 0; o < 8; ++o) acc[o] += wp[tp * 32 + o] * vv;
        }
    }
    if (valid) {
#pragma unroll
        for (int o = 0; o < 8; ++o) {
            int oc = ocg * 8 + o;
            out[((size_t)(b * 32 + oc)) * NN + px] = fmaxf(acc[o] + bias[oc], 0.f);
        }
    }
}

// ---------- generic chunked conv3x3 partials ----------
template<int OCT>
__launch_bounds__(256)
__global__ void k_conv_part(const float* __restrict__ in, const float* __restrict__ wre,
                            const float* __restrict__ attscale,
                            float* __restrict__ part, int Cin, int OC, int nocg,
                            int nchunks, int icchunk, float padval) {
    int bx = blockIdx.x;
    int pxb = bx % PXB2; bx /= PXB2;
    int ocg = bx % nocg; bx /= nocg;
    int chunk = bx % nchunks;
    int b = bx / nchunks;
    int px = pxb * 256 + threadIdx.x;
    bool valid = px < NN;
    int xx0 = px % WW, yy0 = px / WW;

    float acc[OCT];
#pragma unroll
    for (int o = 0; o < OCT; ++o) acc[o] = 0.f;

    int ic0 = chunk * icchunk;
    int ic1 = ic0 + icchunk; if (ic1 > Cin) ic1 = Cin;

    for (int ic = ic0; ic < ic1; ++ic) {
        const float* ip = in + ((size_t)(b * Cin + ic)) * NN;
        float attv = attscale ? attscale[b * Cin + ic] : 1.f;
        float v[9];
#pragma unroll
        for (int ky = 0; ky < 3; ++ky) {
            int yy = yy0 + ky - 1;
#pragma unroll
            for (int kx = 0; kx < 3; ++kx) {
                int xx = xx0 + kx - 1;
                bool ok = valid && yy >= 0 && yy < HH && xx < WW && xx >= 0;
                v[ky * 3 + kx] = ok ? ip[yy * WW + xx] * attv : padval;
            }
        }
        const float* wp = wre + (size_t)ic * 9 * OC + ocg * OCT;
#pragma unroll
        for (int tp = 0; tp < 9; ++tp) {
            float vv = v[tp];
#pragma unroll
            for (int o = 0; o < OCT; ++o) acc[o] += wp[tp * OC + o] * vv;
        }
    }
    if (valid) {
#pragma unroll
        for (int o = 0; o < OCT; ++o)
            part[(((size_t)chunk * BB + b) * OC + ocg * OCT + o) * NN + px] = acc[o];
    }
}

// ---------- reduce chunks + bias + relu (dec path) ----------
__global__ void k_conv_reduce(const float* __restrict__ part, const float* __restrict__ bias,
                              float* __restrict__ out, float* __restrict__ xTout,
                              int OCr, int nchunks) {
    int idx = blockIdx.x * blockDim.x + threadIdx.x;
    int total = BB * OCr * NN;
    if (idx >= total) return;
    int px = idx % NN;
    int oc = (idx / NN) % OCr;
    int b = idx / (NN * OCr);
    float s = bias[oc];
    for (int c = 0; c < nchunks; ++c)
        s += part[(((size_t)c * BB + b) * OCr + oc) * NN + px];
    s = fmaxf(s, 0.f);
    if (out)   out[((size_t)(b * OCr + oc)) * NN + px] = s;
    if (xTout) xTout[((size_t)b * NN + px) * OCr + oc] = s;
}

// ---------- dec conv2 (32->1): 4-wave ic-split, 64 px per block ----------
__launch_bounds__(256)
__global__ void k_conv_dec2(const float* __restrict__ in, const float* __restrict__ wre,
                            const float* __restrict__ bias, float* __restrict__ out) {
    __shared__ float red[4][64];
    int tid = threadIdx.x;
    int w = tid >> 6, lane = tid & 63;
    int blk = blockIdx.x;               // BB * 40
    int pxb = blk % 40;
    int b = blk / 40;
    int px = pxb * 64 + lane;
    bool valid = px < NN;
    int xx0 = px % WW, yy0 = px / WW;
    float acc = 0.f;
    for (int ic = w * 8; ic < w * 8 + 8; ++ic) {
        const float* ip = in + ((size_t)(b * 32 + ic)) * NN;
#pragma unroll
        for (int ky = 0; ky < 3; ++ky) {
            int yy = yy0 + ky - 1;
#pragma unroll
            for (int kx = 0; kx < 3; ++kx) {
                int xx = xx0 + kx - 1;
                bool ok = valid && yy >= 0 && yy < HH && xx >= 0 && xx < WW;
                float v = ok ? ip[yy * WW + xx] : -999.0f;
                acc += v * wre[ic * 9 + ky * 3 + kx];
            }
        }
    }
    red[w][lane] = acc;
    __syncthreads();
    if (w == 0 && valid) {
        float s = red[0][lane] + red[1][lane] + red[2][lane] + red[3][lane];
        out[(size_t)b * NN + px] = fmaxf(s + bias[0], 0.f);
    }
}

// ---------- fused adjacency build + compact (+ repack in tail blocks) ----------
// __launch_bounds__(256, 8): cap VGPR so the S-streaming rows get 8 waves/SIMD.
__launch_bounds__(256, 8)
__global__ void k_build_compact(const float* __restrict__ S,
                                int2* __restrict__ adjC, int* __restrict__ cntC,
                                const float* __restrict__ e1, const float* __restrict__ e2,
                                const float* __restrict__ dd1, const float* __restrict__ dd2,
                                float* __restrict__ r1, float* __restrict__ r2,
                                float* __restrict__ r3, float* __restrict__ r4) {
    int row = blockIdx.x;               // 2*BB*NN rows; tail blocks do repack
    if (row >= 2 * BB * NN) {
        int i = (row - 2 * BB * NN) * 256 + threadIdx.x;
        if (i < 32 * 3 * 9)  { int oc = i / 27;  int rem = i % 27;  int ic = rem / 9; int tp = rem % 9; r1[(ic * 9 + tp) * 32 + oc] = e1[i]; }
        if (i < 32 * 32 * 9) { int oc = i / 288; int rem = i % 288; int ic = rem / 9; int tp = rem % 9; r2[(ic * 9 + tp) * 32 + oc] = e2[i]; }
        if (i < 32 * 128 * 9){ int oc = i / 1152;int rem = i % 1152;int ic = rem / 9; int tp = rem % 9; r3[(ic * 9 + tp) * 32 + oc] = dd1[i]; }
        if (i < 1 * 32 * 9)  { int oc = 0;       int rem = i;       int ic = rem / 9; int tp = rem % 9; r4[(ic * 9 + tp) * 1  + oc] = dd2[i]; }
        return;
    }
    __shared__ int2 stage[4][WCAP];
    __shared__ int  wcnt[4];

    int i = row % NN;
    int b = (row / NN) % BB;
    int s = row / (NN * BB);
    const float4* Srow = (const float4*)(S + (((size_t)(b * 2 + s)) * NN + i) * NN);

    int tid = threadIdx.x;
    int w = tid >> 6, lane = tid & 63;
    int q0 = w * 157;
    int q1 = (w == 3) ? 625 : (q0 + 157);

    float4 fv[3];
#pragma unroll
    for (int r = 0; r < 3; ++r) {
        int q = q0 + r * 64 + lane;
        fv[r] = (q < q1) ? Srow[q] : make_float4(0.f, 0.f, 0.f, 0.f);
    }

    unsigned long long below = (lane == 63) ? 0x7fffffffffffffffull
                                            : ((1ull << lane) - 1ull);
    int cnt = 0;
#pragma unroll
    for (int r = 0; r < 3; ++r) {
        float4 f = fv[r];
        unsigned long long b0 = __ballot(fabsf(f.x) > ZTOL);
        unsigned long long b1 = __ballot(fabsf(f.y) > ZTOL);
        unsigned long long b2 = __ballot(fabsf(f.z) > ZTOL);
        unsigned long long b3 = __ballot(fabsf(f.w) > ZTOL);
        int rk = __popcll(b0 & below) + __popcll(b1 & below) +
                 __popcll(b2 & below) + __popcll(b3 & below);
        int j0 = (q0 + r * 64 + lane) * 4;
        int idx = cnt + rk;
        if ((b0 >> lane) & 1) { if (idx < WCAP) stage[w][idx] = make_int2(j0 + 0, __float_as_int(f.x)); ++idx; }
        if ((b1 >> lane) & 1) { if (idx < WCAP) stage[w][idx] = make_int2(j0 + 1, __float_as_int(f.y)); ++idx; }
        if ((b2 >> lane) & 1) { if (idx < WCAP) stage[w][idx] = make_int2(j0 + 2, __float_as_int(f.z)); ++idx; }
        if ((b3 >> lane) & 1) { if (idx < WCAP) stage[w][idx] = make_int2(j0 + 3, __float_as_int(f.w)); ++idx; }
        cnt += __popcll(b0) + __popcll(b1) + __popcll(b2) + __popcll(b3);
    }
    if (lane == 0) wcnt[w] = (cnt < WCAP) ? cnt : WCAP;
    __syncthreads();

    int c0 = wcnt[0], c1 = wcnt[1], c2 = wcnt[2], c3 = wcnt[3];
    int base = (w == 0) ? 0 : (w == 1) ? c0 : (w == 2) ? (c0 + c1) : (c0 + c1 + c2);
    int myc = wcnt[w];
    for (int k = lane; k < myc; k += 64) {
        int dstb = base + k;
        if (dstb < ADJW) adjC[(size_t)row * ADJW + dstb] = stage[w][k];
    }
    if (tid == 0) {
        int total = c0 + c1 + c2 + c3;
        cntC[row] = (total < ADJW) ? total : ADJW;
    }
}

// ---------- per-head masked softmax * S ----------
__device__ __forceinline__ float4 softmax4(float4 s1f, float4 s2f, int lane, int cnt, float valr) {
    float e[PP] = { s1f.x + s2f.x, s1f.y + s2f.y, s1f.z + s2f.z, s1f.w + s2f.w };
    float w[PP];
#pragma unroll
    for (int p = 0; p < PP; ++p) {
        float v = e[p];
        v = (v < 0.f) ? LRELU_SLOPE * v : v;
        v = (lane < cnt) ? v : -1e30f;
        float mx = v;
#pragma unroll
        for (int m = 32; m >= 1; m >>= 1) mx = fmaxf(mx, __shfl_xor(mx, m));
        float ex = (lane < cnt) ? expf(v - mx) : 0.f;
        float sm = ex;
#pragma unroll
        for (int m = 32; m >= 1; m >>= 1) sm += __shfl_xor(sm, m);
        w[p] = (cnt > 0) ? ex / sm * valr : 0.f;
    }
    return make_float4(w[0], w[1], w[2], w[3]);
}

// ---------- emit s1/s2 (lane holds y element `lane`, PF<=64) ----------
template<int PF>
__device__ __forceinline__ void emit_one(const float* __restrict__ a,
                                         float4* __restrict__ s1E, float4* __restrict__ s2E,
                                         float yl, int lane, int node) {
    float r1[PP], r2[PP];
#pragma unroll
    for (int p = 0; p < PP; ++p) {
        float v1 = (lane < PF) ? a[p * 2 * PF + lane] * yl : 0.f;
        float v2 = (lane < PF) ? a[p * 2 * PF + PF + lane] * yl : 0.f;
#pragma unroll
        for (int m = 32; m >= 1; m >>= 1) { v1 += __shfl_xor(v1, m); v2 += __shfl_xor(v2, m); }
        r1[p] = v1; r2[p] = v2;
    }
    if (lane == 0) {
        s1E[node] = make_float4(r1[0], r1[1], r1[2], r1[3]);
        s2E[node] = make_float4(r2[0], r2[1], r2[2], r2[3]);
    }
}

// ---------- unified GAT layer v6: ONE WAVE = ONE BLOCK = ONE NODE (grid 5000) ----------
template<int G, int F, int FZ, int ADDP, int ES, int CMAJ>
__launch_bounds__(64)
__global__ void k_gat_layer2(const float* __restrict__ xT,
                             const int2* __restrict__ adjC, const int* __restrict__ cntC,
                             const float4* __restrict__ s1A, const float4* __restrict__ s2A,
                             const float4* __restrict__ s1Z, const float4* __restrict__ s2Z,
                             const float* __restrict__ Wf, const float* __restrict__ bias,
                             const float* __restrict__ WfZ, const float* __restrict__ biasZ,
                             const float* __restrict__ prevP,
                             float* __restrict__ auxOut,
                             const float* __restrict__ aE0, float4* __restrict__ s1E0, float4* __restrict__ s2E0,
                             const float* __restrict__ aE1, float4* __restrict__ s1E1, float4* __restrict__ s2E1,
                             float* __restrict__ dst) {
    constexpr int PF = PP * F;
    __shared__ int    csh[64];
    __shared__ float4 wAsh[64];
    __shared__ float4 wZsh[FZ ? 64 : 1];
    __shared__ float  xAsh[G + 1];
    __shared__ float  z1Ash[PP][G + 1];
    __shared__ float  z1Zsh[FZ ? PP : 1][FZ ? (G + 1) : 1];
    __shared__ float  ysh[ES ? (PF + 1) : 1];

    int lane = threadIdx.x;
    int node = blockIdx.x;
    int b = node / NN, i = node % NN;

    // ---- sparse phase ----
    {
        if (lane < G) xAsh[lane] = xT[(size_t)node * G + lane];
        int cnt = cntC[node];
        int colr = 0; float valr = 0.f;
        if (lane < cnt) {
            int2 e = adjC[(size_t)node * ADJW + lane];
            colr = e.x;
            valr = __int_as_float(e.y);
        }
        float4 s2fA = make_float4(0.f, 0.f, 0.f, 0.f);
        float4 s2fZ = make_float4(0.f, 0.f, 0.f, 0.f);
        if (lane < cnt) {
            s2fA = s2A[(size_t)b * NN + colr];
            if constexpr (FZ > 0) s2fZ = s2Z[(size_t)b * NN + colr];
        }
        csh[lane] = colr;
        wAsh[lane] = softmax4(s1A[node], s2fA, lane, cnt, valr);
        if constexpr (FZ > 0) wZsh[lane] = softmax4(s1Z[node], s2fZ, lane, cnt, valr);

        constexpr int STEP = (G == 32) ? 2 : 1;
        int sl = (G == 32) ? (lane >> 5) : 0;
        int g  = (G == 32) ? (lane & 31) : lane;
        const float* xb = xT + (size_t)b * NN * G + g;
        float zA[PP] = {0.f, 0.f, 0.f, 0.f};
        float zZ[PP] = {0.f, 0.f, 0.f, 0.f};
        int jj = sl;
        for (; jj + 7 * STEP < cnt; jj += 8 * STEP) {
            int c[8];
            float xv[8];
#pragma unroll
            for (int u = 0; u < 8; ++u) c[u] = csh[jj + u * STEP];
#pragma unroll
            for (int u = 0; u < 8; ++u) xv[u] = xb[(size_t)c[u] * G];
#pragma unroll
            for (int u = 0; u < 8; ++u) {
                float4 wa = wAsh[jj + u * STEP];
                zA[0] += wa.x * xv[u]; zA[1] += wa.y * xv[u];
                zA[2] += wa.z * xv[u]; zA[3] += wa.w * xv[u];
                if constexpr (FZ > 0) {
                    float4 wz = wZsh[jj + u * STEP];
                    zZ[0] += wz.x * xv[u]; zZ[1] += wz.y * xv[u];
                    zZ[2] += wz.z * xv[u]; zZ[3] += wz.w * xv[u];
                }
            }
        }
        for (; jj < cnt; jj += STEP) {
            float xv = xb[(size_t)csh[jj] * G];
            float4 wa = wAsh[jj];
            zA[0] += wa.x * xv; zA[1] += wa.y * xv; zA[2] += wa.z * xv; zA[3] += wa.w * xv;
            if constexpr (FZ > 0) {
                float4 wz = wZsh[jj];
                zZ[0] += wz.x * xv; zZ[1] += wz.y * xv; zZ[2] += wz.z * xv; zZ[3] += wz.w * xv;
            }
        }
        if (G == 32) {
#pragma unroll
            for (int p = 0; p < PP; ++p) {
                zA[p] += __shfl_xor(zA[p], 32);
                if constexpr (FZ > 0) zZ[p] += __shfl_xor(zZ[p], 32);
            }
        }
        if (sl == 0) {
#pragma unroll
            for (int p = 0; p < PP; ++p) {
                z1Ash[p][g] = zA[p];
                if constexpr (FZ > 0) z1Zsh[p][g] = zZ[p];
            }
        }
    }
    // same-wave LDS deps are in-order; no barrier needed.

    // ---- dense own projection: W direct from global (L2-cached) ----
    for (int t = lane; t < PF; t += 64) {
        int p = t / F, f = t % F;
        const float* W0 = Wf + (size_t)(p * 2) * G * F + f;
        const float* W1 = W0 + G * F;
        float y = bias[f];
#pragma unroll 16
        for (int g = 0; g < G; ++g)
            y += xAsh[g] * W0[(size_t)g * F] + z1Ash[p][g] * W1[(size_t)g * F];
        if (ADDP) y += prevP[(size_t)node * PF + t];
        if (CMAJ) dst[((size_t)(b * PF + t)) * NN + i] = y;
        else      dst[(size_t)node * PF + t] = y;
        if (ES) ysh[t] = y;
    }

    // ---- aux projection (second attention set, same x/adjacency) ----
    if constexpr (FZ > 0) {
        for (int t = lane; t < PP * FZ; t += 64) {
            int p = t / FZ, f = t % FZ;
            const float* V0 = WfZ + (size_t)(p * 2) * G * FZ + f;
            const float* V1 = V0 + G * FZ;
            float y = biasZ[f];
#pragma unroll 16
            for (int g = 0; g < G; ++g)
                y += xAsh[g] * V0[(size_t)g * FZ] + z1Zsh[p][g] * V1[(size_t)g * FZ];
            auxOut[(size_t)node * (PP * FZ) + t] = y;
        }
    }

    // ---- s1/s2 emit for next layer(s) ----
    if (ES) {
        float yl = (lane < PF) ? ysh[lane] : 0.f;
        emit_one<PF>(aE0, s1E0, s2E0, yl, lane, node);
        if (ES >= 2) emit_one<PF>(aE1, s1E1, s2E1, yl, lane, node);
    }
}

// ---------- s1/s2 for f0 FUSED with enc2 chunk-reduce ----------
template<int G>
__launch_bounds__(256)
__global__ void k_s1s2T_fused(const float* __restrict__ part, const float* __restrict__ bias,
                              float* __restrict__ xTout,
                              const float* __restrict__ aA, float4* __restrict__ s1A, float4* __restrict__ s2A,
                              const float* __restrict__ aB, float4* __restrict__ s1B, float4* __restrict__ s2B) {
    constexpr int NPB = 16;
    __shared__ float xsh[NPB][G + 1];
    __shared__ float ash[2][2][PP][G];
    __shared__ float ysh[NPB][17];

    int tid = threadIdx.x;
    int node0 = blockIdx.x * NPB;

    for (int idx = tid; idx < PP * 2 * G; idx += 256) {
        int p = idx / (2 * G), r = idx % (2 * G);
        int which = r / G, g = r % G;
        ash[0][which][p][g] = aA[idx];
        if (aB) ash[1][which][p][g] = aB[idx];
    }
    for (int idx = tid; idx < NPB * G; idx += 256) {
        int nl = idx & (NPB - 1), g = idx >> 4;
        int node = node0 + nl;
        float s = 0.f;
        if (node < BB * NN) {
            int b = node / NN, px = node % NN;
            s = bias[g];
            for (int c = 0; c < 4; ++c)
                s += part[(((size_t)c * BB + b) * G + g) * NN + px];
            s = fmaxf(s, 0.f);
        }
        xsh[nl][g] = s;
    }
    __syncthreads();
    for (int idx = tid; idx < NPB * G; idx += 256) {
        int nl = idx / G, g = idx % G;
        int node = node0 + nl;
        if (node < BB * NN) xTout[(size_t)node * G + g] = xsh[nl][g];
    }

    {
        int nl = tid / 16, o = tid % 16;
        int set = o / 8, which = (o / 4) % 2, p = o % 4;
        float acc = 0.f;
        if (set == 0 || aB) {
#pragma unroll
            for (int g = 0; g < G; ++g) acc += ash[set][which][p][g] * xsh[nl][g];
        }
        ysh[nl][o] = acc;
    }
    __syncthreads();

    if (tid < NPB * 4) {
        int nl = tid / 4, q = tid % 4;
        int node = node0 + nl;
        if (node < BB * NN) {
            int base = (q / 2) * 8 + (q % 2) * 4;
            float4 v = make_float4(ysh[nl][base + 0], ysh[nl][base + 1],
                                   ysh[nl][base + 2], ysh[nl][base + 3]);
            if (q == 0) s1A[node] = v;
            else if (q == 1) s2A[node] = v;
            else if (q == 2) { if (aB) s1B[node] = v; }
            else             { if (aB) s2B[node] = v; }
        }
    }
}

// ---------- att = max over spatial ----------
__global__ void k_attmax(const float* __restrict__ d, float* __restrict__ att) {
    int wid = blockIdx.x;
    int lane = threadIdx.x;
    const float4* row = (const float4*)(d + (size_t)wid * NN);
    float m = -1e30f;
    for (int q = lane; q < 625; q += 64) {
        float4 f = row[q];
        m = fmaxf(m, fmaxf(fmaxf(f.x, f.y), fmaxf(f.z, f.w)));
    }
    for (int s = 32; s >= 1; s >>= 1) m = fmaxf(m, __shfl_xor(m, s));
    if (lane == 0) att[wid] = m;
}

// ---------- channel-attention MLP ----------
__launch_bounds__(128)
__global__ void k_camlp(const float* __restrict__ att,
                        const float* __restrict__ w1, const float* __restrict__ b1,
                        const float* __restrict__ w2, const float* __restrict__ b2,
                        float* __restrict__ attf) {
    __shared__ float a[128];
    __shared__ float h[128];
    int b = blockIdx.x, t = threadIdx.x;
    a[t] = att[b * 128 + t];
    __syncthreads();
    float acc = b1[t];
    const float* wr = w1 + (size_t)t * 128;
    for (int k = 0; k < 128; ++k) acc += a[k] * wr[k];
    h[t] = fmaxf(acc, 0.f);
    __syncthreads();
    float acc2 = b2[t];
    const float* wr2 = w2 + (size_t)t * 128;
    for (int k = 0; k < 128; ++k) acc2 += h[k] * wr2[k];
    attf[b * 128 + t] = sigmoidf_(acc2);
}

// ---------- MLP layer 1: fully batched float4 loads ----------
__launch_bounds__(64)
__global__ void k_mlp1(const float* __restrict__ flat, const float* __restrict__ w,
                       const float* __restrict__ bias, float* __restrict__ out) {
    int wid = blockIdx.x;
    int lane = threadIdx.x;
    int o = wid % 512;
    int b = wid / 512;
    const float4* fr = (const float4*)(flat + (size_t)b * NN);     // 625 quads
    const float4* wr = (const float4*)(w + (size_t)o * NN);
    float4 fv[10], wv[10];
#pragma unroll
    for (int k = 0; k < 10; ++k) {
        int q = lane + 64 * k;
        bool ok = q < 625;
        fv[k] = ok ? fr[q] : make_float4(0.f, 0.f, 0.f, 0.f);
        wv[k] = ok ? wr[q] : make_float4(0.f, 0.f, 0.f, 0.f);
    }
    float acc = 0.f;
#pragma unroll
    for (int k = 0; k < 10; ++k)
        acc += fv[k].x * wv[k].x + fv[k].y * wv[k].y +
               fv[k].z * wv[k].z + fv[k].w * wv[k].w;
    for (int s = 32; s >= 1; s >>= 1) acc += __shfl_xor(acc, s);
    if (lane == 0) out[wid] = fmaxf(acc + bias[o], 0.0f);
}

__global__ void k_mlp2(const float* __restrict__ m, const float* __restrict__ w,
                       const float* __restrict__ bias, float* __restrict__ out) {
    int wid = blockIdx.x;
    int lane = threadIdx.x;
    int o = wid % 5;
    int b = wid / 5;
    const float* mr = m + b * 512;
    const float* wr = w + o * 512;
    float acc = 0.f;
    for (int k = lane; k < 512; k += 64) acc += mr[k] * wr[k];
    for (int s = 32; s >= 1; s >>= 1) acc += __shfl_xor(acc, s);
    if (lane == 0) out[wid] = 1.0f / (1.0f + expf(-(acc + bias[o])));
}

extern "C" void kernel_launch(void* const* d_in, const int* in_sizes, int n_in,
                              void* d_out, int out_size, void* d_ws, size_t ws_size,
                              hipStream_t stream) {
    const float* x       = (const float*)d_in[0];
    const float* Slist   = (const float*)d_in[1];
    const float* enc_w1  = (const float*)d_in[2];
    const float* enc_b1  = (const float*)d_in[3];
    const float* enc_w2  = (const float*)d_in[4];
    const float* enc_b2  = (const float*)d_in[5];
    const float* d0_a = (const float*)d_in[6];  const float* d0_W = (const float*)d_in[7];  const float* d0_b = (const float*)d_in[8];
    const float* d1_a = (const float*)d_in[9];  const float* d1_W = (const float*)d_in[10]; const float* d1_b = (const float*)d_in[11];
    const float* u0_a = (const float*)d_in[12]; const float* u0_W = (const float*)d_in[13]; const float* u0_b = (const float*)d_in[14];
    const float* u1_a = (const float*)d_in[15]; const float* u1_W = (const float*)d_in[16]; const float* u1_b = (const float*)d_in[17];
    const float* s0_a = (const float*)d_in[18]; const float* s0_W = (const float*)d_in[19]; const float* s0_b = (const float*)d_in[20];
    const float* s1_a = (const float*)d_in[21]; const float* s1_W = (const float*)d_in[22]; const float* s1_b = (const float*)d_in[23];
    const float* ca_w1 = (const float*)d_in[24]; const float* ca_b1 = (const float*)d_in[25];
    const float* ca_w2 = (const float*)d_in[26]; const float* ca_b2 = (const float*)d_in[27];
    const float* dec_w1 = (const float*)d_in[28]; const float* dec_b1 = (const float*)d_in[29];
    const float* dec_w2 = (const float*)d_in[30]; const float* dec_b2 = (const float*)d_in[31];
    const float* mlp_w1 = (const float*)d_in[32]; const float* mlp_b1 = (const float*)d_in[33];
    const float* mlp_w2 = (const float*)d_in[34]; const float* mlp_b2 = (const float*)d_in[35];
    float* out = (float*)d_out;

    // ---- workspace layout (f32 elements) ----
    float* ws = (float*)d_ws;
    size_t off = 0;
    auto alloc = [&](size_t n) { float* p = ws + off; off += n; return p; };
    float* h1    = alloc((size_t)BB * 32 * NN);
    float* xT_f0 = alloc((size_t)BB * NN * 32);
    float* xT_f1 = alloc((size_t)BB * NN * 64);
    float* xT_f2 = alloc((size_t)BB * NN * 32);
    float* xT_g1 = alloc((size_t)BB * NN * 64);
    float* g2    = alloc((size_t)BB * 128 * NN);
    int2*  adjC = (int2*)alloc((size_t)2 * BB * NN * ADJW * 2);
    int*   cntC = (int*)alloc((size_t)2 * BB * NN);
    float4* s1_d0 = (float4*)alloc(4 * BB * NN); float4* s2_d0 = (float4*)alloc(4 * BB * NN);
    float4* s1_s0 = (float4*)alloc(4 * BB * NN); float4* s2_s0 = (float4*)alloc(4 * BB * NN);
    float4* s1_d1 = (float4*)alloc(4 * BB * NN); float4* s2_d1 = (float4*)alloc(4 * BB * NN);
    float4* s1_sc1= (float4*)alloc(4 * BB * NN); float4* s2_sc1= (float4*)alloc(4 * BB * NN);
    float4* s1_u0 = (float4*)alloc(4 * BB * NN); float4* s2_u0 = (float4*)alloc(4 * BB * NN);
    float4* s1_u1 = (float4*)alloc(4 * BB * NN); float4* s2_u1 = (float4*)alloc(4 * BB * NN);
    float* g1p   = alloc((size_t)BB * NN * 64);
    float* g2p   = alloc((size_t)BB * NN * 128);
    float* att   = alloc(BB * 128);
    float* attf  = alloc(BB * 128);
    float* dec1o = alloc((size_t)BB * 32 * NN);
    float* dec2o = alloc((size_t)BB * NN);
    float* mbuf  = alloc((size_t)BB * 512);
    float* wre1  = alloc(32 * 3 * 9);
    float* wre2  = alloc(32 * 32 * 9);
    float* wre3  = alloc(32 * 128 * 9);
    float* wre4  = alloc(1 * 32 * 9);
    float* partial = alloc((size_t)8 * BB * 32 * NN);
    (void)ws_size;

    const int T = 256;
    const int NNODE = BB * NN;          // 5000
    const int2* adjC0 = adjC;
    const int2* adjC1 = adjC + (size_t)NNODE * ADJW;
    const int* cnt0 = cntC;
    const int* cnt1 = cntC + NNODE;

    // 0. fused adjacency build+compact + weight repack (tail blocks)
    k_build_compact<<<2 * NNODE + 144, 256, 0, stream>>>(Slist, adjC, cntC,
                                                         enc_w1, enc_w2, dec_w1, dec_w2,
                                                         wre1, wre2, wre3, wre4);
    // 1. encoder
    k_conv_enc1<<<BB * 4 * PXB2, 256, 0, stream>>>(x, wre1, enc_b1, h1);
    k_conv_part<8><<<BB * 4 * 4 * PXB2, 256, 0, stream>>>(h1, wre2, nullptr, partial,
                                                          32, 32, 4, 4, 8, 0.0f);
    // 2. s1/s2 on f0 (fused enc2 chunk-reduce) for d0 + s0
    k_s1s2T_fused<32><<<cdiv(NNODE, 16), 256, 0, stream>>>(partial, enc_b2, xT_f0,
                                                           d0_a, s1_d0, s2_d0,
                                                           s0_a, s1_s0, s2_s0);
    // 3. L1: f1 = gat(f0,S0,d0); aux s0-proj -> g2p; emit d1, sc1
    k_gat_layer2<32,16,32, 0, 2, 0><<<NNODE, 64, 0, stream>>>(
        xT_f0, adjC0, cnt0,
        s1_d0, s2_d0, s1_s0, s2_s0,
        d0_W, d0_b, s0_W, s0_b,
        nullptr, g2p,
        d1_a, s1_d1, s2_d1, s1_a, s1_sc1, s2_sc1, xT_f1);
    // 4. L2: f2 = gat(f1,S1,d1); aux sc1-proj -> g1p; emit u0
    k_gat_layer2<64,8,16, 0, 1, 0><<<NNODE, 64, 0, stream>>>(
        xT_f1, adjC1, cnt1,
        s1_d1, s2_d1, s1_sc1, s2_sc1,
        d1_W, d1_b, s1_W, s1_b,
        nullptr, g1p,
        u0_a, s1_u0, s2_u0, nullptr, nullptr, nullptr, xT_f2);
    // 5. L3: g1 = gat(f2,S1,u0) + g1p; emit u1
    k_gat_layer2<32,16,0, 1, 1, 0><<<NNODE, 64, 0, stream>>>(
        xT_f2, adjC1, cnt1,
        s1_u0, s2_u0, nullptr, nullptr,
        u0_W, u0_b, nullptr, nullptr,
        g1p, nullptr,
        u1_a, s1_u1, s2_u1, nullptr, nullptr, nullptr, xT_g1);
    // 6. L4: g2 = gat(g1,S0,u1) + g2p  (channel-major out)
    k_gat_layer2<64,32,0, 1, 0, 1><<<NNODE, 64, 0, stream>>>(
        xT_g1, adjC0, cnt0,
        s1_u1, s2_u1, nullptr, nullptr,
        u1_W, u1_b, nullptr, nullptr,
        g2p, nullptr,
        nullptr, nullptr, nullptr, nullptr, nullptr, nullptr, g2);
    // 7. channel attention (scale fused into dec conv1)
    k_attmax<<<BB * 128, 64, 0, stream>>>(g2, att);
    k_camlp<<<BB, 128, 0, stream>>>(att, ca_w1, ca_b1, ca_w2, ca_b2, attf);
    // 8. decoder convs (pad -999)
    k_conv_part<16><<<BB * 8 * 2 * PXB2, 256, 0, stream>>>(g2, wre3, attf, partial,
                                                           128, 32, 2, 8, 16, -999.0f);
    k_conv_reduce<<<cdiv(BB * 32 * NN, T), T, 0, stream>>>(partial, dec_b1, dec1o, nullptr, 32, 8);
    k_conv_dec2<<<BB * 40, 256, 0, stream>>>(dec1o, wre4, dec_b2, dec2o);
    // 9. MLP head
    k_mlp1<<<BB * 512, 64, 0, stream>>>(dec2o, mlp_w1, mlp_b1, mbuf);
    k_mlp2<<<BB * 5, 64, 0, stream>>>(mbuf, mlp_w2, mlp_b2, out);
}